// Round 6
// baseline (3341.158 us; speedup 1.0000x reference)
//
#include <hip/hip_runtime.h>
#include <hip/hip_cooperative_groups.h>
#include <hip/hip_fp16.h>
#include <cstdint>
#include <cstddef>

namespace cg = cooperative_groups;

// Sinkhorn OT loss, B=4096, D=512.
// Round 6: persistent cooperative iteration kernel. K scaled fp16 in LDS
// stripes (16 rows/block x 256 blocks = whole 32MB matrix resident in LDS).
// Scaling: Ks = K*2^26 (fp16-safe), a~ = a*2^24 -> u~ = 2^{-2} u, v~ = v,
// gamma~ = 2^24 gamma, loss = (sum gamma~ c)/2^24, c = REG*(26 ln2 - ln Ks).
// eps folded exactly: e_u = 1e-9*2^26, e_v = 1e-9*2^24.
// ws: Ksg fp16 [0,32MB) | colpart fp16 [32,34) | tpart f32 [34,38) |
//     vglob fp16 @38MB | Xe @40MB | Ye @54MB | Xs,Ys @68MB

#define N_B 4096
#define N_D 512
#define KE  1536
#define REG_ 0.05f
#define LN2_ 0.693147180559945f
#define S_LOG 26.0f                 // Ks = K * 2^26
#define A_SC 4096.0f                // (1/4096) * 2^24
#define EPS_U 0.067108864f          // 1e-9 * 2^26
#define EPS_V 0.016777216f          // 1e-9 * 2^24
#define OUT_SCALE 5.9604644775e-8f  // 2^-24

typedef __attribute__((ext_vector_type(8))) short bs8;
typedef __attribute__((ext_vector_type(8))) unsigned short us8;
typedef __attribute__((ext_vector_type(4))) float f32x4;
typedef __attribute__((ext_vector_type(2))) _Float16 h2;
typedef __attribute__((ext_vector_type(8))) _Float16 h8;

__device__ __forceinline__ float bf2f(unsigned short u) {
  union { uint32_t i; float f; } x; x.i = ((uint32_t)u) << 16; return x.f;
}
__device__ __forceinline__ unsigned short f2bf(float f) {
  union { float f; uint32_t i; } x; x.f = f;
  uint32_t r = (x.i + 0x7FFFu + ((x.i >> 16) & 1u)) >> 16;
  return (unsigned short)r;
}
__device__ __forceinline__ float wave_reduce_sum(float x) {
#pragma unroll
  for (int off = 32; off > 0; off >>= 1) x += __shfl_down(x, off);
  return x;
}

// Expanded operands: Xe=[hi|lo|hi], Ye=[hi|hi|lo] -> K-sum gives
// hi*hi + lo*hi + hi*lo (lo*lo negligible).
__global__ __launch_bounds__(256) void prep_kernel(const float* __restrict__ X,
                                                   const float* __restrict__ Y,
                                                   unsigned short* __restrict__ Xe,
                                                   unsigned short* __restrict__ Ye) {
  int idx = (blockIdx.x * 256 + threadIdx.x) * 8;
  int row = idx >> 9, col = idx & 511;
  size_t base = (size_t)row * KE + col;
  float fx[8], fy[8];
  *(float4*)&fx[0] = *(const float4*)&X[idx];
  *(float4*)&fx[4] = *(const float4*)&X[idx + 4];
  *(float4*)&fy[0] = *(const float4*)&Y[idx];
  *(float4*)&fy[4] = *(const float4*)&Y[idx + 4];
  us8 xh, xl, yh, yl;
#pragma unroll
  for (int k = 0; k < 8; ++k) {
    unsigned short h = f2bf(fx[k]);
    xh[k] = h; xl[k] = f2bf(fx[k] - bf2f(h));
    unsigned short g = f2bf(fy[k]);
    yh[k] = g; yl[k] = f2bf(fy[k] - bf2f(g));
  }
  *(us8*)&Xe[base] = xh; *(us8*)&Xe[base + 512] = xl; *(us8*)&Xe[base + 1024] = xh;
  *(us8*)&Ye[base] = yh; *(us8*)&Ye[base + 512] = yh; *(us8*)&Ye[base + 1024] = yl;
}

__global__ __launch_bounds__(256) void rownorm_kernel(const float* __restrict__ X,
                                                      float* __restrict__ out) {
  int row = blockIdx.x * 4 + (threadIdx.x >> 6);
  int lane = threadIdx.x & 63;
  const float4* Xr = (const float4*)(X + (size_t)row * N_D);
  float acc = 0.f;
#pragma unroll
  for (int k = lane; k < N_D / 4; k += 64) {
    float4 a = Xr[k];
    acc += a.x * a.x + a.y * a.y + a.z * a.z + a.w * a.w;
  }
  acc = wave_reduce_sum(acc);
  if (lane == 0) out[row] = acc;
}

// 128x128-tile MFMA GEMM: C = Xe . Ye^T over KE=1536,
// epilogue: cost=max(0,Xs+Ys-2C); Ks=exp(26*ln2 - cost/REG) -> fp16.
__global__ __launch_bounds__(256) void gemm_costK(const unsigned short* __restrict__ Xe,
                                                  const unsigned short* __restrict__ Ye,
                                                  const float* __restrict__ Xs,
                                                  const float* __restrict__ Ys,
                                                  _Float16* __restrict__ Ksg) {
  __shared__ unsigned short As[128 * 32];
  __shared__ unsigned short Bs[128 * 32];
  const int tid = threadIdx.x;
  const int lane = tid & 63, w = tid >> 6;
  const int wr = w >> 1, wc = w & 1;
  const int row0 = blockIdx.y * 128, col0 = blockIdx.x * 128;

  f32x4 acc[4][4];
#pragma unroll
  for (int i = 0; i < 4; ++i)
#pragma unroll
    for (int j = 0; j < 4; ++j) acc[i][j] = (f32x4)(0.0f);

  const int srow = tid >> 2;
  const int scol = (tid & 3) * 8;

  for (int k0 = 0; k0 < KE; k0 += 32) {
#pragma unroll
    for (int c = 0; c < 2; ++c) {
      int r = srow + c * 64;
      const unsigned short* ga = Xe + (size_t)(row0 + r) * KE + k0 + scol;
      const unsigned short* gb = Ye + (size_t)(col0 + r) * KE + k0 + scol;
      char* la = (char*)As + c * 4096 + w * 1024;
      char* lb = (char*)Bs + c * 4096 + w * 1024;
      __builtin_amdgcn_global_load_lds((const __attribute__((address_space(1))) void*)ga,
                                       (__attribute__((address_space(3))) void*)la, 16, 0, 0);
      __builtin_amdgcn_global_load_lds((const __attribute__((address_space(1))) void*)gb,
                                       (__attribute__((address_space(3))) void*)lb, 16, 0, 0);
    }
    __syncthreads();
    bs8 af[4], bfr[4];
#pragma unroll
    for (int f = 0; f < 4; ++f) {
      af[f]  = *(const bs8*)&As[(wr * 64 + f * 16 + (lane & 15)) * 32 + (lane >> 4) * 8];
      bfr[f] = *(const bs8*)&Bs[(wc * 64 + f * 16 + (lane & 15)) * 32 + (lane >> 4) * 8];
    }
#pragma unroll
    for (int i = 0; i < 4; ++i)
#pragma unroll
      for (int j = 0; j < 4; ++j)
        acc[i][j] = __builtin_amdgcn_mfma_f32_16x16x32_bf16(af[i], bfr[j], acc[i][j], 0, 0, 0);
    __syncthreads();
  }

#pragma unroll
  for (int j = 0; j < 4; ++j) {
    int col = col0 + wc * 64 + j * 16 + (lane & 15);
    float ys = Ys[col];
#pragma unroll
    for (int i = 0; i < 4; ++i) {
#pragma unroll
      for (int q = 0; q < 4; ++q) {
        int row = row0 + wr * 64 + i * 16 + (lane >> 4) * 4 + q;
        float cost = fmaxf(Xs[row] + ys - 2.0f * acc[i][j][q], 0.0f);
        float ks = expf(S_LOG * LN2_ - fminf(cost, 1000.0f) * (1.0f / REG_));
        Ksg[(size_t)row * N_B + col] = (_Float16)ks;
      }
    }
  }
}

// Persistent cooperative Sinkhorn: 256 blocks x 512 threads, 1 block/CU.
// Block b owns rows [16b,16b+16) of Ks, held in LDS (128KB) for all 50 iters.
__global__ __launch_bounds__(512, 1) void sinkhorn_coop(
    const _Float16* __restrict__ Ksg,
    _Float16* __restrict__ colpart,   // [256][4096] fp16
    float* __restrict__ tpart,        // [256][4096] f32 (last iter only)
    _Float16* __restrict__ vglob,     // [4096] fp16
    float* __restrict__ out) {
  __shared__ _Float16 Kl[16][N_B];    // 128 KB
  __shared__ _Float16 vsh[N_B];       // 8 KB
  __shared__ float ush[16];
  __shared__ float lossp[16];
  cg::grid_group grid = cg::this_grid();
  const int tid = threadIdx.x;
  const int b = blockIdx.x;
  const int wv = tid >> 6, lane = tid & 63;

  // preload stripe: 16 x (512 threads x 16B) = 128 KB, linear.
  const char* gsrc = (const char*)(Ksg + (size_t)b * 16 * N_B);
  char* ldst = (char*)&Kl[0][0];
#pragma unroll
  for (int c = 0; c < 16; ++c) {
    __builtin_amdgcn_global_load_lds(
        (const __attribute__((address_space(1))) void*)(gsrc + c * 8192 + tid * 16),
        (__attribute__((address_space(3))) void*)(ldst + c * 8192 + tid * 16), 16, 0, 0);
  }
  // v_0 = 1
  {
    h8 one;
#pragma unroll
    for (int q = 0; q < 8; ++q) one[q] = (_Float16)1.0f;
    *(h8*)&vsh[tid * 8] = one;
  }
  __syncthreads();

  for (int t = 0; t < 50; ++t) {
    const bool last = (t == 49);
    // ---- phase A: u~ for the block's 16 rows (2 rows/wave), dot2 from LDS
#pragma unroll
    for (int rr = 0; rr < 2; ++rr) {
      int r = wv * 2 + rr;
      float acc = 0.f;
#pragma unroll
      for (int ch = 0; ch < 8; ++ch) {
        int k = ch * 512 + lane * 8;
        h8 kv = *(const h8*)&Kl[r][k];
        h8 vv = *(const h8*)&vsh[k];
#pragma unroll
        for (int q = 0; q < 4; ++q) {
          h2 a2 = {kv[2 * q], kv[2 * q + 1]};
          h2 b2 = {vv[2 * q], vv[2 * q + 1]};
          acc = __builtin_amdgcn_fdot2(a2, b2, acc, false);
        }
      }
      acc = wave_reduce_sum(acc);
      if (lane == 0) ush[r] = A_SC / (acc + EPS_U);
    }
    __syncthreads();

    // ---- phase B: column partials for cols [tid*8, tid*8+8)
    {
      const int c0 = tid * 8;
      h2 vacc[4];
#pragma unroll
      for (int q = 0; q < 4; ++q) vacc[q] = h2{(_Float16)0.f, (_Float16)0.f};
      float tacc[8] = {0.f, 0.f, 0.f, 0.f, 0.f, 0.f, 0.f, 0.f};
#pragma unroll
      for (int r = 0; r < 16; ++r) {
        float uf = ush[r];
        _Float16 uh = (_Float16)uf;
        h2 u2 = {uh, uh};
        h8 kv = *(const h8*)&Kl[r][c0];
#pragma unroll
        for (int q = 0; q < 4; ++q) {
          h2 k2 = {kv[2 * q], kv[2 * q + 1]};
          vacc[q] = k2 * u2 + vacc[q];  // v_pk_fma_f16
        }
        if (last) {
#pragma unroll
          for (int e = 0; e < 8; ++e) {
            float kf = (float)kv[e];
            float cc = REG_ * (S_LOG * LN2_ - logf(fmaxf(kf, 6e-8f)));
            tacc[e] += (uf * kf) * cc;
          }
        }
      }
      h8 vst;
#pragma unroll
      for (int q = 0; q < 4; ++q) { vst[2 * q] = vacc[q][0]; vst[2 * q + 1] = vacc[q][1]; }
      *(h8*)&colpart[(size_t)b * N_B + c0] = vst;
      if (last) {
        *(float4*)&tpart[(size_t)b * N_B + c0] = *(float4*)&tacc[0];
        *(float4*)&tpart[(size_t)b * N_B + c0 + 4] = *(float4*)&tacc[4];
      }
    }
    grid.sync();

    // ---- phase C: reduce own 16 cols over 256 block-partials
    {
      const int g = tid >> 5, l32 = tid & 31;
      const int col = b * 16 + g;
      float s = 0.f;
#pragma unroll
      for (int k = 0; k < 8; ++k)
        s += (float)colpart[(size_t)(l32 + 32 * k) * N_B + col];
#pragma unroll
      for (int off = 16; off > 0; off >>= 1) s += __shfl_down(s, off, 32);
      if (!last) {
        if (l32 == 0) vglob[col] = (_Float16)(A_SC / (s + EPS_V));
      } else {
        float tt = 0.f;
#pragma unroll
        for (int k = 0; k < 8; ++k)
          tt += tpart[(size_t)(l32 + 32 * k) * N_B + col];
#pragma unroll
        for (int off = 16; off > 0; off >>= 1) tt += __shfl_down(tt, off, 32);
        if (l32 == 0) lossp[g] = (A_SC / (s + EPS_V)) * tt;
      }
    }

    if (!last) {
      grid.sync();
      *(h8*)&vsh[tid * 8] = *(const h8*)&vglob[tid * 8];
      __syncthreads();
    }
  }

  __syncthreads();
  if (tid == 0) {
    float s = 0.f;
#pragma unroll
    for (int g = 0; g < 16; ++g) s += lossp[g];
    atomicAdd(out, s * OUT_SCALE);
  }
}

extern "C" void kernel_launch(void* const* d_in, const int* in_sizes, int n_in,
                              void* d_out, int out_size, void* d_ws, size_t ws_size,
                              hipStream_t stream) {
  const float* X = (const float*)d_in[0];
  const float* Y = (const float*)d_in[1];
  float* out = (float*)d_out;
  char* w = (char*)d_ws;

  const size_t MB = 1024 * 1024;
  _Float16* Ksg     = (_Float16*)w;                 // 32 MB
  _Float16* colpart = (_Float16*)(w + 32 * MB);     // 2 MB
  float*    tpart   = (float*)(w + 34 * MB);        // 4 MB
  _Float16* vglob   = (_Float16*)(w + 38 * MB);     // 8 KB
  unsigned short* Xe = (unsigned short*)(w + 40 * MB);  // 12.6 MB
  unsigned short* Ye = (unsigned short*)(w + 54 * MB);  // 12.6 MB
  float* Xs = (float*)(w + 68 * MB);
  float* Ys = Xs + N_B;

  hipMemsetAsync(d_out, 0, sizeof(float), stream);

  prep_kernel<<<N_B * N_D / (256 * 8), 256, 0, stream>>>(X, Y, Xe, Ye);
  rownorm_kernel<<<N_B / 4, 256, 0, stream>>>(X, Xs);
  rownorm_kernel<<<N_B / 4, 256, 0, stream>>>(Y, Ys);

  gemm_costK<<<dim3(32, 32), 256, 0, stream>>>(Xe, Ye, Xs, Ys, Ksg);

  void* kargs[] = {(void*)&Ksg, (void*)&colpart, (void*)&tpart, (void*)&vglob, (void*)&out};
  hipLaunchCooperativeKernel((void*)sinkhorn_coop, dim3(256), dim3(512), kargs, 0, stream);
}

// Round 7
// 2944.924 us; speedup vs baseline: 1.1345x; 1.1345x over previous
//
#include <hip/hip_runtime.h>
#include <hip/hip_cooperative_groups.h>
#include <hip/hip_fp16.h>
#include <cstdint>
#include <cstddef>

namespace cg = cooperative_groups;

// Sinkhorn OT loss, B=4096, D=512.
// Round 7: persistent cooperative kernel, symmetric row/col ownership.
// Block b holds rows [16b,16b+16) of Ks (fp8) AND of Ks^T (fp8) in LDS.
// Per iter: phase A -> 16 u entries -> 32B write -> grid.sync -> 8KB coalesced
// gather; phase B -> 16 v entries -> 32B write -> grid.sync -> gather.
// NO partial-matrix reductions, NO strided cross-XCD reads (round-6 failure).
// Scaling: Ks = K*2^26 (fp8 e5m2 range ~[3e-4, 60]), a~ = a*2^24:
//   u~ = a~/(sum Ks v~ + 1e-9*2^26), v~ = a~/(sum KsT u~ + 1e-9*2^24)
//   loss = 2^-24 * sum u~ Ks v~ c,  c = REG*(26 ln2 - ln Ks)  (fp8-byte LUT).
// ws: Km fp8 16MB @0 | KTm fp8 16MB @16MB | uglob/vglob fp16 @32MB |
//     Xe @33MB | Ye @48MB | Xs,Ys @64MB

#define N_B 4096
#define N_D 512
#define KE  1536
#define REG_ 0.05f
#define LN2_ 0.693147180559945f
#define S_LOG 26.0f                 // Ks = K * 2^26
#define A_SC 4096.0f                // (1/4096) * 2^24
#define EPS_U 0.067108864f          // 1e-9 * 2^26
#define EPS_V 0.016777216f          // 1e-9 * 2^24
#define OUT_SCALE 5.9604644775e-8f  // 2^-24

typedef __attribute__((ext_vector_type(8))) short bs8;
typedef __attribute__((ext_vector_type(8))) unsigned short us8;
typedef __attribute__((ext_vector_type(4))) float f32x4;
typedef __attribute__((ext_vector_type(2))) _Float16 h2;
typedef __attribute__((ext_vector_type(8))) _Float16 h8;

__device__ __forceinline__ float bf2f(unsigned short u) {
  union { uint32_t i; float f; } x; x.i = ((uint32_t)u) << 16; return x.f;
}
__device__ __forceinline__ unsigned short f2bf(float f) {
  union { float f; uint32_t i; } x; x.f = f;
  uint32_t r = (x.i + 0x7FFFu + ((x.i >> 16) & 1u)) >> 16;
  return (unsigned short)r;
}
// e5m2 = top byte of fp16 (RNE). Clamp first so rounding can't hit inf.
__device__ __forceinline__ unsigned char f2fp8(float f) {
  f = fminf(f, 57344.0f);
  __half h = __float2half(f);
  unsigned short hb = *(unsigned short*)&h;
  unsigned short r = (unsigned short)((hb + 0x7F + ((hb >> 8) & 1)) >> 8);
  return (unsigned char)r;
}
__device__ __forceinline__ h2 as_h2(uint32_t x) {
  union { uint32_t u; h2 h; } c; c.u = x; return c.h;
}
__device__ __forceinline__ float wave_reduce_sum(float x) {
#pragma unroll
  for (int off = 32; off > 0; off >>= 1) x += __shfl_down(x, off);
  return x;
}

// Expanded operands: Xe=[hi|lo|hi], Ye=[hi|hi|lo] -> K-sum gives
// hi*hi + lo*hi + hi*lo (lo*lo negligible).
__global__ __launch_bounds__(256) void prep_kernel(const float* __restrict__ X,
                                                   const float* __restrict__ Y,
                                                   unsigned short* __restrict__ Xe,
                                                   unsigned short* __restrict__ Ye) {
  int idx = (blockIdx.x * 256 + threadIdx.x) * 8;
  int row = idx >> 9, col = idx & 511;
  size_t base = (size_t)row * KE + col;
  float fx[8], fy[8];
  *(float4*)&fx[0] = *(const float4*)&X[idx];
  *(float4*)&fx[4] = *(const float4*)&X[idx + 4];
  *(float4*)&fy[0] = *(const float4*)&Y[idx];
  *(float4*)&fy[4] = *(const float4*)&Y[idx + 4];
  us8 xh, xl, yh, yl;
#pragma unroll
  for (int k = 0; k < 8; ++k) {
    unsigned short h = f2bf(fx[k]);
    xh[k] = h; xl[k] = f2bf(fx[k] - bf2f(h));
    unsigned short g = f2bf(fy[k]);
    yh[k] = g; yl[k] = f2bf(fy[k] - bf2f(g));
  }
  *(us8*)&Xe[base] = xh; *(us8*)&Xe[base + 512] = xl; *(us8*)&Xe[base + 1024] = xh;
  *(us8*)&Ye[base] = yh; *(us8*)&Ye[base + 512] = yh; *(us8*)&Ye[base + 1024] = yl;
}

__global__ __launch_bounds__(256) void rownorm_kernel(const float* __restrict__ X,
                                                      float* __restrict__ out) {
  int row = blockIdx.x * 4 + (threadIdx.x >> 6);
  int lane = threadIdx.x & 63;
  const float4* Xr = (const float4*)(X + (size_t)row * N_D);
  float acc = 0.f;
#pragma unroll
  for (int k = lane; k < N_D / 4; k += 64) {
    float4 a = Xr[k];
    acc += a.x * a.x + a.y * a.y + a.z * a.z + a.w * a.w;
  }
  acc = wave_reduce_sum(acc);
  if (lane == 0) out[row] = acc;
}

// 128x128-tile MFMA GEMM: C = Xe . Ye^T over KE=1536,
// epilogue: cost=max(0,Xs+Ys-2C); Ks=exp(26*ln2 - cost/REG) -> fp8 e5m2.
__global__ __launch_bounds__(256) void gemm_costK(const unsigned short* __restrict__ Xe,
                                                  const unsigned short* __restrict__ Ye,
                                                  const float* __restrict__ Xs,
                                                  const float* __restrict__ Ys,
                                                  unsigned char* __restrict__ Km) {
  __shared__ unsigned short As[128 * 32];
  __shared__ unsigned short Bs[128 * 32];
  const int tid = threadIdx.x;
  const int lane = tid & 63, w = tid >> 6;
  const int wr = w >> 1, wc = w & 1;
  const int row0 = blockIdx.y * 128, col0 = blockIdx.x * 128;

  f32x4 acc[4][4];
#pragma unroll
  for (int i = 0; i < 4; ++i)
#pragma unroll
    for (int j = 0; j < 4; ++j) acc[i][j] = (f32x4)(0.0f);

  const int srow = tid >> 2;
  const int scol = (tid & 3) * 8;

  for (int k0 = 0; k0 < KE; k0 += 32) {
#pragma unroll
    for (int c = 0; c < 2; ++c) {
      int r = srow + c * 64;
      const unsigned short* ga = Xe + (size_t)(row0 + r) * KE + k0 + scol;
      const unsigned short* gb = Ye + (size_t)(col0 + r) * KE + k0 + scol;
      char* la = (char*)As + c * 4096 + w * 1024;
      char* lb = (char*)Bs + c * 4096 + w * 1024;
      __builtin_amdgcn_global_load_lds((const __attribute__((address_space(1))) void*)ga,
                                       (__attribute__((address_space(3))) void*)la, 16, 0, 0);
      __builtin_amdgcn_global_load_lds((const __attribute__((address_space(1))) void*)gb,
                                       (__attribute__((address_space(3))) void*)lb, 16, 0, 0);
    }
    __syncthreads();
    bs8 af[4], bfr[4];
#pragma unroll
    for (int f = 0; f < 4; ++f) {
      af[f]  = *(const bs8*)&As[(wr * 64 + f * 16 + (lane & 15)) * 32 + (lane >> 4) * 8];
      bfr[f] = *(const bs8*)&Bs[(wc * 64 + f * 16 + (lane & 15)) * 32 + (lane >> 4) * 8];
    }
#pragma unroll
    for (int i = 0; i < 4; ++i)
#pragma unroll
      for (int j = 0; j < 4; ++j)
        acc[i][j] = __builtin_amdgcn_mfma_f32_16x16x32_bf16(af[i], bfr[j], acc[i][j], 0, 0, 0);
    __syncthreads();
  }

#pragma unroll
  for (int j = 0; j < 4; ++j) {
    int col = col0 + wc * 64 + j * 16 + (lane & 15);
    float ys = Ys[col];
#pragma unroll
    for (int i = 0; i < 4; ++i) {
#pragma unroll
      for (int q = 0; q < 4; ++q) {
        int row = row0 + wr * 64 + i * 16 + (lane >> 4) * 4 + q;
        float cost = fmaxf(Xs[row] + ys - 2.0f * acc[i][j][q], 0.0f);
        float ks = expf(S_LOG * LN2_ - fminf(cost, 1000.0f) * (1.0f / REG_));
        Km[(size_t)row * N_B + col] = f2fp8(ks);
      }
    }
  }
}

// 64x64 byte-tile transpose for fp8 K.
__global__ __launch_bounds__(256) void transpose_fp8(const unsigned char* __restrict__ in,
                                                     unsigned char* __restrict__ out) {
  __shared__ unsigned char t[64][68];
  const int tid = threadIdx.x;
  const int r0 = blockIdx.y * 64, c0 = blockIdx.x * 64;
  {
    int r = tid >> 2, off = (tid & 3) * 16;
    uint4 m = *(const uint4*)&in[(size_t)(r0 + r) * N_B + c0 + off];
    *(uint4*)&t[r][off] = m;
  }
  __syncthreads();
  {
    int j = tid >> 2, off = (tid & 3) * 16;
    unsigned char b[16];
#pragma unroll
    for (int k = 0; k < 16; ++k) b[k] = t[off + k][j];
    *(uint4*)&out[(size_t)(c0 + j) * N_B + r0 + off] = *(uint4*)b;
  }
}

// Persistent cooperative Sinkhorn. 256 blocks x 512 threads, 1 block/CU.
// LDS: KrowS 64KB + KcolS 64KB + vsh 8KB + ush 8KB + c_lut 1KB = 145KB.
__global__ __launch_bounds__(512, 1) void sinkhorn_coop(
    const unsigned char* __restrict__ Krow_g,   // fp8 Ks rows
    const unsigned char* __restrict__ Kcol_g,   // fp8 Ks^T rows
    _Float16* __restrict__ uglob,               // [4096]
    _Float16* __restrict__ vglob,               // [4096]
    float* __restrict__ out) {
  __shared__ unsigned char KrowS[16 * N_B];
  __shared__ unsigned char KcolS[16 * N_B];
  __shared__ _Float16 vsh[N_B];
  __shared__ _Float16 ush[N_B];
  __shared__ float c_lut[256];
  __shared__ float lossp[16];
  cg::grid_group grid = cg::this_grid();
  const int tid = threadIdx.x;
  const int b = blockIdx.x;
  const int wv = tid >> 6, lane = tid & 63;

  // preload 64KB + 64KB, linear, 16B/thread x 8 passes each
  {
    const char* ga = (const char*)(Krow_g + (size_t)b * 16 * N_B);
    const char* gb = (const char*)(Kcol_g + (size_t)b * 16 * N_B);
    char* la = (char*)KrowS;
    char* lb = (char*)KcolS;
#pragma unroll
    for (int p = 0; p < 8; ++p) {
      __builtin_amdgcn_global_load_lds(
          (const __attribute__((address_space(1))) void*)(ga + p * 8192 + tid * 16),
          (__attribute__((address_space(3))) void*)(la + p * 8192 + tid * 16), 16, 0, 0);
      __builtin_amdgcn_global_load_lds(
          (const __attribute__((address_space(1))) void*)(gb + p * 8192 + tid * 16),
          (__attribute__((address_space(3))) void*)(lb + p * 8192 + tid * 16), 16, 0, 0);
    }
  }
  // c_lut: cost per fp8 byte; 0 for K<=0 (gamma=0 contribution)
  if (tid < 256) {
    unsigned short hb = (unsigned short)(tid << 8);
    float kf = __half2float(*(__half*)&hb);
    c_lut[tid] = (kf > 0.f) ? REG_ * (S_LOG * LN2_ - logf(kf)) : 0.f;
  }
  // v0 = 1
  {
    h8 one;
#pragma unroll
    for (int q = 0; q < 8; ++q) one[q] = (_Float16)1.0f;
    *(h8*)&vsh[tid * 8] = one;
  }
  __syncthreads();

  for (int t = 0; t < 50; ++t) {
    const bool last = (t == 49);
    // ---- phase A: u~ for the block's 16 rows; wave wv -> rows 2wv, 2wv+1
#pragma unroll
    for (int rr = 0; rr < 2; ++rr) {
      const int r = wv * 2 + rr;
      const uint32_t* Kr = (const uint32_t*)&KrowS[r * N_B];
      float acc = 0.f;
#pragma unroll
      for (int p = 0; p < 16; ++p) {
        uint32_t d = Kr[lane + 64 * p];
        int vb = (lane + 64 * p) * 4;
        h2 v01 = *(const h2*)&vsh[vb];
        h2 v23 = *(const h2*)&vsh[vb + 2];
        h2 k02 = as_h2((d << 8) & 0xFF00FF00u);   // {e0, e2}
        h2 k13 = as_h2(d & 0xFF00FF00u);          // {e1, e3}
        h2 v02 = {v01[0], v23[0]};
        h2 v13 = {v01[1], v23[1]};
        acc = __builtin_amdgcn_fdot2(k02, v02, acc, false);
        acc = __builtin_amdgcn_fdot2(k13, v13, acc, false);
      }
      acc = wave_reduce_sum(acc);
      if (lane == 0) uglob[b * 16 + r] = (_Float16)(A_SC / (acc + EPS_U));
    }
    grid.sync();
    *(h8*)&ush[tid * 8] = *(const h8*)&uglob[tid * 8];
    __syncthreads();

    // ---- phase B: v~ for the block's 16 cols (rows of KsT)
#pragma unroll
    for (int rr = 0; rr < 2; ++rr) {
      const int r = wv * 2 + rr;
      const uint32_t* Kc = (const uint32_t*)&KcolS[r * N_B];
      float acc = 0.f, tac = 0.f;
      if (!last) {
#pragma unroll
        for (int p = 0; p < 16; ++p) {
          uint32_t d = Kc[lane + 64 * p];
          int ub = (lane + 64 * p) * 4;
          h2 u01 = *(const h2*)&ush[ub];
          h2 u23 = *(const h2*)&ush[ub + 2];
          h2 k02 = as_h2((d << 8) & 0xFF00FF00u);
          h2 k13 = as_h2(d & 0xFF00FF00u);
          h2 u02 = {u01[0], u23[0]};
          h2 u13 = {u01[1], u23[1]};
          acc = __builtin_amdgcn_fdot2(k02, u02, acc, false);
          acc = __builtin_amdgcn_fdot2(k13, u13, acc, false);
        }
      } else {
#pragma unroll
        for (int p = 0; p < 16; ++p) {
          uint32_t d = Kc[lane + 64 * p];
          int ub = (lane + 64 * p) * 4;
          h2 u01 = *(const h2*)&ush[ub];
          h2 u23 = *(const h2*)&ush[ub + 2];
          h2 k02 = as_h2((d << 8) & 0xFF00FF00u);
          h2 k13 = as_h2(d & 0xFF00FF00u);
          h2 u02 = {u01[0], u23[0]};
          h2 u13 = {u01[1], u23[1]};
          acc = __builtin_amdgcn_fdot2(k02, u02, acc, false);
          acc = __builtin_amdgcn_fdot2(k13, u13, acc, false);
          tac += (float)u01[0] * (float)k02[0] * c_lut[d & 0xFF] +
                 (float)u01[1] * (float)k13[0] * c_lut[(d >> 8) & 0xFF] +
                 (float)u23[0] * (float)k02[1] * c_lut[(d >> 16) & 0xFF] +
                 (float)u23[1] * (float)k13[1] * c_lut[(d >> 24) & 0xFF];
        }
      }
      acc = wave_reduce_sum(acc);
      if (!last) {
        if (lane == 0) vglob[b * 16 + r] = (_Float16)(A_SC / (acc + EPS_V));
      } else {
        tac = wave_reduce_sum(tac);
        if (lane == 0) lossp[r] = (A_SC / (acc + EPS_V)) * tac;
      }
    }
    if (!last) {
      grid.sync();
      *(h8*)&vsh[tid * 8] = *(const h8*)&vglob[tid * 8];
      __syncthreads();
    }
  }

  __syncthreads();
  if (tid == 0) {
    float s = 0.f;
#pragma unroll
    for (int g = 0; g < 16; ++g) s += lossp[g];
    atomicAdd(out, s * OUT_SCALE);
  }
}

extern "C" void kernel_launch(void* const* d_in, const int* in_sizes, int n_in,
                              void* d_out, int out_size, void* d_ws, size_t ws_size,
                              hipStream_t stream) {
  const float* X = (const float*)d_in[0];
  const float* Y = (const float*)d_in[1];
  float* out = (float*)d_out;
  char* w = (char*)d_ws;

  const size_t MB = 1024 * 1024;
  unsigned char* Km  = (unsigned char*)w;             // 16 MB
  unsigned char* KTm = (unsigned char*)(w + 16 * MB); // 16 MB
  _Float16* uglob = (_Float16*)(w + 32 * MB);         // 8 KB
  _Float16* vglob = uglob + N_B;                      // 8 KB
  unsigned short* Xe = (unsigned short*)(w + 33 * MB);
  unsigned short* Ye = (unsigned short*)(w + 48 * MB);
  float* Xs = (float*)(w + 64 * MB);
  float* Ys = Xs + N_B;

  hipMemsetAsync(d_out, 0, sizeof(float), stream);

  prep_kernel<<<N_B * N_D / (256 * 8), 256, 0, stream>>>(X, Y, Xe, Ye);
  rownorm_kernel<<<N_B / 4, 256, 0, stream>>>(X, Xs);
  rownorm_kernel<<<N_B / 4, 256, 0, stream>>>(Y, Ys);

  gemm_costK<<<dim3(32, 32), 256, 0, stream>>>(Xe, Ye, Xs, Ys, Km);
  transpose_fp8<<<dim3(64, 64), 256, 0, stream>>>(Km, KTm);

  void* kargs[] = {(void*)&Km, (void*)&KTm, (void*)&uglob, (void*)&vglob, (void*)&out};
  hipLaunchCooperativeKernel((void*)sinkhorn_coop, dim3(256), dim3(512), kargs, 0, stream);
}

// Round 10
// 1588.342 us; speedup vs baseline: 2.1036x; 1.8541x over previous
//
#include <hip/hip_runtime.h>
#include <hip/hip_cooperative_groups.h>
#include <hip/hip_fp16.h>
#include <cstdint>
#include <cstddef>

namespace cg = cooperative_groups;

// Sinkhorn OT loss, B=4096, D=512.
// Round 8 (2nd resubmit): round-7 persistent structure (fp8 row+col stripes
// in LDS, symmetric ownership) but grid.sync replaced by a custom 2-level
// barrier:
//  - u/v exchanged ONLY via agent-scope atomics (execute at LLC, never in L2
//    -> no stale lines, no cache flush needed)
//  - K stripes live in LDS -> immune to any cache maintenance
//  - barrier: 16 padded group counters + master + monotonic epoch; u-stores
//    issued by wave 0 lanes 0..15, thread 0 (same wave) does RELEASE arrive
//    so its vmcnt drain covers them.
// Scaling identical to r7: Ks = K*2^26 fp8 e5m2, a~ = a*2^24,
//   loss = 2^-24 * sum u~ Ks v~ c, c = REG*(26 ln2 - ln Ks) via byte LUT.
// ws: Km 16MB @0 | KTm @16MB | bar @32MB (4KB) | uglob @32MB+4KB (16KB f32) |
//     vglob next | Xe @33MB | Ye @48MB | Xs,Ys @64MB

#define N_B 4096
#define N_D 512
#define KE  1536
#define REG_ 0.05f
#define LN2_ 0.693147180559945f
#define S_LOG 26.0f
#define A_SC 4096.0f                // (1/4096) * 2^24
#define EPS_U 0.067108864f          // 1e-9 * 2^26
#define EPS_V 0.016777216f          // 1e-9 * 2^24
#define OUT_SCALE 5.9604644775e-8f  // 2^-24
#define CSTR 32                     // barrier counter stride (128B)

typedef __attribute__((ext_vector_type(8))) short bs8;
typedef __attribute__((ext_vector_type(8))) unsigned short us8;
typedef __attribute__((ext_vector_type(4))) float f32x4;
typedef __attribute__((ext_vector_type(2))) _Float16 h2;
typedef __attribute__((ext_vector_type(8))) _Float16 h8;

__device__ __forceinline__ float bf2f(unsigned short u) {
  union { uint32_t i; float f; } x; x.i = ((uint32_t)u) << 16; return x.f;
}
__device__ __forceinline__ unsigned short f2bf(float f) {
  union { float f; uint32_t i; } x; x.f = f;
  uint32_t r = (x.i + 0x7FFFu + ((x.i >> 16) & 1u)) >> 16;
  return (unsigned short)r;
}
__device__ __forceinline__ unsigned char f2fp8(float f) {
  f = fminf(f, 57344.0f);
  __half h = __float2half(f);
  unsigned short hb = *(unsigned short*)&h;
  unsigned short r = (unsigned short)((hb + 0x7F + ((hb >> 8) & 1)) >> 8);
  return (unsigned char)r;
}
__device__ __forceinline__ h2 as_h2(uint32_t x) {
  union { uint32_t u; h2 h; } c; c.u = x; return c.h;
}
__device__ __forceinline__ float wave_reduce_sum(float x) {
#pragma unroll
  for (int off = 32; off > 0; off >>= 1) x += __shfl_down(x, off);
  return x;
}

__global__ __launch_bounds__(256) void prep_kernel(const float* __restrict__ X,
                                                   const float* __restrict__ Y,
                                                   unsigned short* __restrict__ Xe,
                                                   unsigned short* __restrict__ Ye) {
  int idx = (blockIdx.x * 256 + threadIdx.x) * 8;
  int row = idx >> 9, col = idx & 511;
  size_t base = (size_t)row * KE + col;
  float fx[8], fy[8];
  *(float4*)&fx[0] = *(const float4*)&X[idx];
  *(float4*)&fx[4] = *(const float4*)&X[idx + 4];
  *(float4*)&fy[0] = *(const float4*)&Y[idx];
  *(float4*)&fy[4] = *(const float4*)&Y[idx + 4];
  us8 xh, xl, yh, yl;
#pragma unroll
  for (int k = 0; k < 8; ++k) {
    unsigned short h = f2bf(fx[k]);
    xh[k] = h; xl[k] = f2bf(fx[k] - bf2f(h));
    unsigned short g = f2bf(fy[k]);
    yh[k] = g; yl[k] = f2bf(fy[k] - bf2f(g));
  }
  *(us8*)&Xe[base] = xh; *(us8*)&Xe[base + 512] = xl; *(us8*)&Xe[base + 1024] = xh;
  *(us8*)&Ye[base] = yh; *(us8*)&Ye[base + 512] = yh; *(us8*)&Ye[base + 1024] = yl;
}

__global__ __launch_bounds__(256) void rownorm_kernel(const float* __restrict__ X,
                                                      float* __restrict__ out) {
  int row = blockIdx.x * 4 + (threadIdx.x >> 6);
  int lane = threadIdx.x & 63;
  const float4* Xr = (const float4*)(X + (size_t)row * N_D);
  float acc = 0.f;
#pragma unroll
  for (int k = lane; k < N_D / 4; k += 64) {
    float4 a = Xr[k];
    acc += a.x * a.x + a.y * a.y + a.z * a.z + a.w * a.w;
  }
  acc = wave_reduce_sum(acc);
  if (lane == 0) out[row] = acc;
}

__global__ __launch_bounds__(256) void gemm_costK(const unsigned short* __restrict__ Xe,
                                                  const unsigned short* __restrict__ Ye,
                                                  const float* __restrict__ Xs,
                                                  const float* __restrict__ Ys,
                                                  unsigned char* __restrict__ Km) {
  __shared__ unsigned short As[128 * 32];
  __shared__ unsigned short Bs[128 * 32];
  const int tid = threadIdx.x;
  const int lane = tid & 63, w = tid >> 6;
  const int wr = w >> 1, wc = w & 1;
  const int row0 = blockIdx.y * 128, col0 = blockIdx.x * 128;

  f32x4 acc[4][4];
#pragma unroll
  for (int i = 0; i < 4; ++i)
#pragma unroll
    for (int j = 0; j < 4; ++j) acc[i][j] = (f32x4)(0.0f);

  const int srow = tid >> 2;
  const int scol = (tid & 3) * 8;

  for (int k0 = 0; k0 < KE; k0 += 32) {
#pragma unroll
    for (int c = 0; c < 2; ++c) {
      int r = srow + c * 64;
      const unsigned short* ga = Xe + (size_t)(row0 + r) * KE + k0 + scol;
      const unsigned short* gb = Ye + (size_t)(col0 + r) * KE + k0 + scol;
      char* la = (char*)As + c * 4096 + w * 1024;
      char* lb = (char*)Bs + c * 4096 + w * 1024;
      __builtin_amdgcn_global_load_lds((const __attribute__((address_space(1))) void*)ga,
                                       (__attribute__((address_space(3))) void*)la, 16, 0, 0);
      __builtin_amdgcn_global_load_lds((const __attribute__((address_space(1))) void*)gb,
                                       (__attribute__((address_space(3))) void*)lb, 16, 0, 0);
    }
    __syncthreads();
    bs8 af[4], bfr[4];
#pragma unroll
    for (int f = 0; f < 4; ++f) {
      af[f]  = *(const bs8*)&As[(wr * 64 + f * 16 + (lane & 15)) * 32 + (lane >> 4) * 8];
      bfr[f] = *(const bs8*)&Bs[(wc * 64 + f * 16 + (lane & 15)) * 32 + (lane >> 4) * 8];
    }
#pragma unroll
    for (int i = 0; i < 4; ++i)
#pragma unroll
      for (int j = 0; j < 4; ++j)
        acc[i][j] = __builtin_amdgcn_mfma_f32_16x16x32_bf16(af[i], bfr[j], acc[i][j], 0, 0, 0);
    __syncthreads();
  }

#pragma unroll
  for (int j = 0; j < 4; ++j) {
    int col = col0 + wc * 64 + j * 16 + (lane & 15);
    float ys = Ys[col];
#pragma unroll
    for (int i = 0; i < 4; ++i) {
#pragma unroll
      for (int q = 0; q < 4; ++q) {
        int row = row0 + wr * 64 + i * 16 + (lane >> 4) * 4 + q;
        float cost = fmaxf(Xs[row] + ys - 2.0f * acc[i][j][q], 0.0f);
        float ks = expf(S_LOG * LN2_ - fminf(cost, 1000.0f) * (1.0f / REG_));
        Km[(size_t)row * N_B + col] = f2fp8(ks);
      }
    }
  }
}

__global__ __launch_bounds__(256) void transpose_fp8(const unsigned char* __restrict__ in,
                                                     unsigned char* __restrict__ out) {
  __shared__ unsigned char t[64][68];
  const int tid = threadIdx.x;
  const int r0 = blockIdx.y * 64, c0 = blockIdx.x * 64;
  {
    int r = tid >> 2, off = (tid & 3) * 16;
    uint4 m = *(const uint4*)&in[(size_t)(r0 + r) * N_B + c0 + off];
    *(uint4*)&t[r][off] = m;
  }
  __syncthreads();
  {
    int j = tid >> 2, off = (tid & 3) * 16;
    unsigned char b[16];
#pragma unroll
    for (int k = 0; k < 16; ++k) b[k] = t[off + k][j];
    *(uint4*)&out[(size_t)(c0 + j) * N_B + r0 + off] = *(uint4*)b;
  }
}

// 2-level device barrier. bar: [0..15]*CSTR group counters, 16*CSTR master,
// 17*CSTR epoch. Monotonic (no resets). Only thread 0 spins.
__device__ __forceinline__ void gbar(int* bar, int ph) {
  __syncthreads();
  if (threadIdx.x == 0) {
    int g = blockIdx.x & 15;
    int prev = __hip_atomic_fetch_add(&bar[g * CSTR], 1, __ATOMIC_RELEASE,
                                      __HIP_MEMORY_SCOPE_AGENT);
    if (prev == ph * 16 - 1) {
      int pm = __hip_atomic_fetch_add(&bar[16 * CSTR], 1, __ATOMIC_ACQ_REL,
                                      __HIP_MEMORY_SCOPE_AGENT);
      if (pm == ph * 16 - 1) {
        __hip_atomic_store(&bar[17 * CSTR], ph, __ATOMIC_RELEASE,
                           __HIP_MEMORY_SCOPE_AGENT);
      }
    }
    while (__hip_atomic_load(&bar[17 * CSTR], __ATOMIC_ACQUIRE,
                             __HIP_MEMORY_SCOPE_AGENT) < ph) {
      __builtin_amdgcn_s_sleep(2);
    }
  }
  __syncthreads();
}

// Persistent Sinkhorn. 256 blocks x 512 threads, 1 block/CU (LDS ~149KB).
__global__ __launch_bounds__(512, 1) void sinkhorn_coop(
    const unsigned char* __restrict__ Krow_g,
    const unsigned char* __restrict__ Kcol_g,
    float* __restrict__ uglob, float* __restrict__ vglob,
    int* __restrict__ bar, float* __restrict__ out) {
  __shared__ unsigned char KrowS[16 * N_B];
  __shared__ unsigned char KcolS[16 * N_B];
  __shared__ _Float16 vsh[N_B];
  __shared__ _Float16 ush[N_B];
  __shared__ float c_lut[256];
  __shared__ float u_loc[16], v_loc[16], lossp[16];
  const int tid = threadIdx.x;
  const int b = blockIdx.x;
  const int wv = tid >> 6, lane = tid & 63;

  {
    const char* ga = (const char*)(Krow_g + (size_t)b * 16 * N_B);
    const char* gb = (const char*)(Kcol_g + (size_t)b * 16 * N_B);
    char* la = (char*)KrowS;
    char* lb = (char*)KcolS;
#pragma unroll
    for (int p = 0; p < 8; ++p) {
      __builtin_amdgcn_global_load_lds(
          (const __attribute__((address_space(1))) void*)(ga + p * 8192 + tid * 16),
          (__attribute__((address_space(3))) void*)(la + p * 8192 + tid * 16), 16, 0, 0);
      __builtin_amdgcn_global_load_lds(
          (const __attribute__((address_space(1))) void*)(gb + p * 8192 + tid * 16),
          (__attribute__((address_space(3))) void*)(lb + p * 8192 + tid * 16), 16, 0, 0);
    }
  }
  if (tid < 256) {
    unsigned short hb = (unsigned short)(tid << 8);
    float kf = __half2float(*(__half*)&hb);
    c_lut[tid] = (kf > 0.f) ? REG_ * (S_LOG * LN2_ - logf(kf)) : 0.f;
  }
  {
    h8 one;
#pragma unroll
    for (int q = 0; q < 8; ++q) one[q] = (_Float16)1.0f;
    *(h8*)&vsh[tid * 8] = one;
  }
  __syncthreads();

  int ph = 0;
  for (int t = 0; t < 50; ++t) {
    const bool last = (t == 49);
    // ---- phase A: u~ for block's 16 rows
#pragma unroll
    for (int rr = 0; rr < 2; ++rr) {
      const int r = wv * 2 + rr;
      const uint32_t* Kr = (const uint32_t*)&KrowS[r * N_B];
      float acc = 0.f;
#pragma unroll
      for (int p = 0; p < 16; ++p) {
        uint32_t d = Kr[lane + 64 * p];
        int vb = (lane + 64 * p) * 4;
        h2 v01 = *(const h2*)&vsh[vb];
        h2 v23 = *(const h2*)&vsh[vb + 2];
        h2 k02 = as_h2((d << 8) & 0xFF00FF00u);
        h2 k13 = as_h2(d & 0xFF00FF00u);
        h2 v02 = {v01[0], v23[0]};
        h2 v13 = {v01[1], v23[1]};
        acc = __builtin_amdgcn_fdot2(k02, v02, acc, false);
        acc = __builtin_amdgcn_fdot2(k13, v13, acc, false);
      }
      acc = wave_reduce_sum(acc);
      if (lane == 0) u_loc[r] = A_SC / (acc + EPS_U);
    }
    __syncthreads();
    // wave 0 lanes 0..15 publish; thread 0's RELEASE arrive drains them.
    if (tid < 16)
      __hip_atomic_store(&uglob[b * 16 + tid], u_loc[tid], __ATOMIC_RELAXED,
                         __HIP_MEMORY_SCOPE_AGENT);
    gbar(bar, ++ph);
#pragma unroll
    for (int k = 0; k < 8; ++k) {
      float uf = __hip_atomic_load(&uglob[tid + 512 * k], __ATOMIC_RELAXED,
                                   __HIP_MEMORY_SCOPE_AGENT);
      ush[tid + 512 * k] = (_Float16)uf;
    }
    __syncthreads();

    // ---- phase B: v~ for block's 16 cols
#pragma unroll
    for (int rr = 0; rr < 2; ++rr) {
      const int r = wv * 2 + rr;
      const uint32_t* Kc = (const uint32_t*)&KcolS[r * N_B];
      float acc = 0.f, tac = 0.f;
      if (!last) {
#pragma unroll
        for (int p = 0; p < 16; ++p) {
          uint32_t d = Kc[lane + 64 * p];
          int ub = (lane + 64 * p) * 4;
          h2 u01 = *(const h2*)&ush[ub];
          h2 u23 = *(const h2*)&ush[ub + 2];
          h2 k02 = as_h2((d << 8) & 0xFF00FF00u);
          h2 k13 = as_h2(d & 0xFF00FF00u);
          h2 u02 = {u01[0], u23[0]};
          h2 u13 = {u01[1], u23[1]};
          acc = __builtin_amdgcn_fdot2(k02, u02, acc, false);
          acc = __builtin_amdgcn_fdot2(k13, u13, acc, false);
        }
      } else {
#pragma unroll
        for (int p = 0; p < 16; ++p) {
          uint32_t d = Kc[lane + 64 * p];
          int ub = (lane + 64 * p) * 4;
          h2 u01 = *(const h2*)&ush[ub];
          h2 u23 = *(const h2*)&ush[ub + 2];
          h2 k02 = as_h2((d << 8) & 0xFF00FF00u);
          h2 k13 = as_h2(d & 0xFF00FF00u);
          h2 u02 = {u01[0], u23[0]};
          h2 u13 = {u01[1], u23[1]};
          acc = __builtin_amdgcn_fdot2(k02, u02, acc, false);
          acc = __builtin_amdgcn_fdot2(k13, u13, acc, false);
          tac += (float)u01[0] * (float)k02[0] * c_lut[d & 0xFF] +
                 (float)u01[1] * (float)k13[0] * c_lut[(d >> 8) & 0xFF] +
                 (float)u23[0] * (float)k02[1] * c_lut[(d >> 16) & 0xFF] +
                 (float)u23[1] * (float)k13[1] * c_lut[(d >> 24) & 0xFF];
        }
      }
      acc = wave_reduce_sum(acc);
      if (!last) {
        if (lane == 0) v_loc[r] = A_SC / (acc + EPS_V);
      } else {
        tac = wave_reduce_sum(tac);
        if (lane == 0) lossp[r] = (A_SC / (acc + EPS_V)) * tac;
      }
    }
    if (!last) {
      __syncthreads();
      if (tid < 16)
        __hip_atomic_store(&vglob[b * 16 + tid], v_loc[tid], __ATOMIC_RELAXED,
                           __HIP_MEMORY_SCOPE_AGENT);
      gbar(bar, ++ph);
#pragma unroll
      for (int k = 0; k < 8; ++k) {
        float vf = __hip_atomic_load(&vglob[tid + 512 * k], __ATOMIC_RELAXED,
                                     __HIP_MEMORY_SCOPE_AGENT);
        vsh[tid + 512 * k] = (_Float16)vf;
      }
      __syncthreads();
    }
  }

  __syncthreads();
  if (tid == 0) {
    float s = 0.f;
#pragma unroll
    for (int g = 0; g < 16; ++g) s += lossp[g];
    atomicAdd(out, s * OUT_SCALE);
  }
}

extern "C" void kernel_launch(void* const* d_in, const int* in_sizes, int n_in,
                              void* d_out, int out_size, void* d_ws, size_t ws_size,
                              hipStream_t stream) {
  const float* X = (const float*)d_in[0];
  const float* Y = (const float*)d_in[1];
  float* out = (float*)d_out;
  char* w = (char*)d_ws;

  const size_t MB = 1024 * 1024;
  unsigned char* Km  = (unsigned char*)w;
  unsigned char* KTm = (unsigned char*)(w + 16 * MB);
  int*   bar   = (int*)(w + 32 * MB);                   // 4 KB (zeroed below)
  float* uglob = (float*)(w + 32 * MB + 4096);          // 16 KB
  float* vglob = uglob + N_B;                           // 16 KB
  unsigned short* Xe = (unsigned short*)(w + 33 * MB);
  unsigned short* Ye = (unsigned short*)(w + 48 * MB);
  float* Xs = (float*)(w + 64 * MB);
  float* Ys = Xs + N_B;

  hipMemsetAsync(d_out, 0, sizeof(float), stream);
  hipMemsetAsync(bar, 0, 4096, stream);

  prep_kernel<<<N_B * N_D / (256 * 8), 256, 0, stream>>>(X, Y, Xe, Ye);
  rownorm_kernel<<<N_B / 4, 256, 0, stream>>>(X, Xs);
  rownorm_kernel<<<N_B / 4, 256, 0, stream>>>(Y, Ys);

  gemm_costK<<<dim3(32, 32), 256, 0, stream>>>(Xe, Ye, Xs, Ys, Km);
  transpose_fp8<<<dim3(64, 64), 256, 0, stream>>>(Km, KTm);

  void* kargs[] = {(void*)&Km, (void*)&KTm, (void*)&uglob, (void*)&vglob,
                   (void*)&bar, (void*)&out};
  hipLaunchCooperativeKernel((void*)sinkhorn_coop, dim3(256), dim3(512), kargs, 0, stream);
}